// Round 5
// baseline (198.189 us; speedup 1.0000x reference)
//
#include <hip/hip_runtime.h>
#include <math.h>

// FocalLoss (rotated-box RetinaNet style), MI355X.
// B=8 images, A=120000 anchors, C=9 classes, M=64 annotations.
// out = [mean cls_loss, mean reg_loss] (2 floats).

constexpr int Bn = 8, An = 120000, Cn = 9, Mn = 64;

// ws layout: per image 4 floats: [cls_sum, reg_sum, pos_count, pad]
__global__ __launch_bounds__(256) void focal_main(
    const float* __restrict__ cls,
    const float* __restrict__ reg,
    const float* __restrict__ anchors,
    const float* __restrict__ ann,
    float* __restrict__ ws)
{
    // SoA ann tile: 0:x1 1:y1 2:x2 3:y2 4:clsval(used as "angle" too)
    //               5:valid 6:area 7:sin 8:cos
    __shared__ float sA[9][Mn];
    __shared__ float sred[4][3];

    const int tid = threadIdx.x;
    const int b = blockIdx.y;
    const int i = blockIdx.x * 256 + tid;

    if (tid < Mn) {
        const float* a6 = ann + ((size_t)b * Mn + tid) * 6;
        float x1 = a6[0], y1 = a6[1], x2 = a6[2], y2 = a6[3];
        float cv = a6[4], fl = a6[5];
        sA[0][tid] = x1; sA[1][tid] = y1; sA[2][tid] = x2; sA[3][tid] = y2;
        sA[4][tid] = cv;
        sA[5][tid] = (fl != -1.0f) ? 1.0f : 0.0f;
        sA[6][tid] = (x2 - x1) * (y2 - y1);
        float sb, cb;
        sincosf(cv, &sb, &cb);
        sA[7][tid] = sb; sA[8][tid] = cb;
    }
    __syncthreads();

    float csum = 0.f, rsum = 0.f, pcnt = 0.f;

    if (i < An) {
        const float* a5 = anchors + (size_t)i * 5;
        const float ax1 = a5[0], ay1 = a5[1], ax2 = a5[2], ay2 = a5[3];
        const float aang = a5[4];
        const float area_a = (ax2 - ax1) * (ay2 - ay1);
        float sa, ca;
        sincosf(aang, &sa, &ca);

        // argmax of ariou = (inter/ua) * |sin(aang - bang)| over valid anns.
        // Track as rational (best_a / best_b); strict-greater -> first-occurrence,
        // matching jnp.argmax. best_a = -1 marks "no valid ann seen".
        float best_a = -1.0f, best_b = 1.0f;
        int best_k = 0;

        #pragma unroll 4
        for (int k = 0; k < Mn; ++k) {
            float bx1 = sA[0][k], by1 = sA[1][k];
            float bx2 = sA[2][k], by2 = sA[3][k];
            float valid = sA[5][k], area_b = sA[6][k];
            float sb = sA[7][k], cb = sA[8][k];
            float iw = fminf(ax2, bx2) - fmaxf(ax1, bx1);
            float ih = fminf(ay2, by2) - fmaxf(ay1, by1);
            iw = fmaxf(iw, 0.f); ih = fmaxf(ih, 0.f);
            float inter = iw * ih;
            float ua = fmaxf(area_a + area_b - inter, 1e-8f);
            // cos(|d| - pi/2) == sin(|d|) == |sin(d)| for |d| <= pi (holds here)
            float s = fabsf(sa * cb - ca * sb);
            float av = inter * s;
            bool upd = (valid != 0.f) && (av * best_b > best_a * ua);
            best_a = upd ? av : best_a;
            best_b = upd ? ua : best_b;
            best_k = upd ? k : best_k;
        }

        float iou_max = (best_a >= 0.f) ? (best_a / best_b) : -1e9f;
        bool pos = iou_max >= 0.5f;
        bool neg = iou_max < 0.4f;

        int ci = (int)sA[4][best_k];

        if (pos || neg) {
            const float* pc = cls + ((size_t)b * An + i) * (size_t)Cn;
            #pragma unroll
            for (int c = 0; c < Cn; ++c) {
                float p = fminf(fmaxf(pc[c], 1e-4f), 0.9999f);
                if (pos && c == ci) {
                    float q = 1.f - p;
                    csum += 0.25f * q * q * (-logf(p));
                } else {
                    csum += 0.75f * p * p * (-logf(1.f - p));
                }
            }
        }

        if (pos) {
            pcnt = 1.f;
            float gx1 = sA[0][best_k], gy1 = sA[1][best_k];
            float gx2 = sA[2][best_k], gy2 = sA[3][best_k];
            float gang = sA[4][best_k];
            float aw = ax2 - ax1, ah = ay2 - ay1;
            float acx = ax1 + 0.5f * aw, acy = ay1 + 0.5f * ah;
            float gwr = gx2 - gx1, ghr = gy2 - gy1;
            float gcx = gx1 + 0.5f * gwr, gcy = gy1 + 0.5f * ghr;
            float gw = fmaxf(gwr, 1.f), gh = fmaxf(ghr, 1.f);
            float tt[5];
            tt[0] = ((gcx - acx) / aw) / 0.1f;
            tt[1] = ((gcy - acy) / ah) / 0.1f;
            tt[2] = logf(gw / aw) / 0.2f;
            tt[3] = logf(gh / ah) / 0.2f;
            tt[4] = tanf(gang - aang);
            const float* rg = reg + ((size_t)b * An + i) * 5;
            #pragma unroll
            for (int j = 0; j < 5; ++j) {
                float d = fabsf(tt[j] - rg[j]);
                rsum += (d <= (1.f / 9.f)) ? (4.5f * d * d) : (d - (0.5f / 9.f));
            }
        }
    }

    // wave reduce (64 lanes) then cross-wave via LDS
    #pragma unroll
    for (int off = 32; off > 0; off >>= 1) {
        csum += __shfl_down(csum, off, 64);
        rsum += __shfl_down(rsum, off, 64);
        pcnt += __shfl_down(pcnt, off, 64);
    }
    const int wave = tid >> 6;
    if ((tid & 63) == 0) {
        sred[wave][0] = csum; sred[wave][1] = rsum; sred[wave][2] = pcnt;
    }
    __syncthreads();
    if (tid == 0) {
        float c = sred[0][0] + sred[1][0] + sred[2][0] + sred[3][0];
        float r = sred[0][1] + sred[1][1] + sred[2][1] + sred[3][1];
        float p = sred[0][2] + sred[1][2] + sred[2][2] + sred[3][2];
        atomicAdd(&ws[b * 4 + 0], c);
        atomicAdd(&ws[b * 4 + 1], r);
        atomicAdd(&ws[b * 4 + 2], p);
    }
}

__global__ void focal_final(const float* __restrict__ ann,
                            const float* __restrict__ ws,
                            float* __restrict__ out)
{
    const int t = threadIdx.x;
    float cl = 0.f, rl = 0.f;
    if (t < Bn) {
        bool has = false;
        for (int k = 0; k < Mn; ++k)
            has = has || (ann[((size_t)t * Mn + k) * 6 + 5] != -1.0f);
        float cs = ws[t * 4 + 0], rs = ws[t * 4 + 1], np = ws[t * 4 + 2];
        if (has) {
            cl = cs / fmaxf(np, 1.f);
            rl = (np > 0.f) ? rs / fmaxf(np * 5.f, 1.f) : 0.f;
        }
    }
    #pragma unroll
    for (int off = 32; off > 0; off >>= 1) {
        cl += __shfl_down(cl, off, 64);
        rl += __shfl_down(rl, off, 64);
    }
    if (t == 0) {
        out[0] = cl / (float)Bn;
        out[1] = rl / (float)Bn;
    }
}

extern "C" void kernel_launch(void* const* d_in, const int* in_sizes, int n_in,
                              void* d_out, int out_size, void* d_ws, size_t ws_size,
                              hipStream_t stream) {
    const float* cls     = (const float*)d_in[0];  // (B, A, C)
    const float* reg     = (const float*)d_in[1];  // (B, A, 5)
    const float* anchors = (const float*)d_in[2];  // (1, A, 5)
    const float* ann     = (const float*)d_in[3];  // (B, M, 6)
    float* out = (float*)d_out;
    float* ws  = (float*)d_ws;

    hipMemsetAsync(ws, 0, Bn * 4 * sizeof(float), stream);

    dim3 grid((An + 255) / 256, Bn);
    focal_main<<<grid, 256, 0, stream>>>(cls, reg, anchors, ann, ws);
    focal_final<<<1, 64, 0, stream>>>(ann, ws, out);
}

// Round 6
// 126.349 us; speedup vs baseline: 1.5686x; 1.5686x over previous
//
#include <hip/hip_runtime.h>
#include <math.h>

// FocalLoss (rotated-box RetinaNet style), MI355X.
// B=8 images, A=120000 anchors, C=9 classes, M=64 annotations.
// out = [mean cls_loss, mean reg_loss] (2 floats).
//
// R5 structure: R=4 anchors/thread; ann tile packed as 2xfloat4 in LDS
// (2 ds_read_b128 per k, shared across 4 anchors = 12x less LDS traffic
// than R4's 9 ds_read_b32 per anchor). Invalid anns stored as zeros so
// the argmax loop needs no validity test (av==0 never beats bestA>=0 on
// strict-greater; best_k divergence only possible when iou_max<0.5 where
// `assigned` is unused). Per-block partials in ws (no atomics, no memset).

constexpr int Bn = 8, An = 120000, Cn = 9, Mn = 64;
constexpr int R = 4;                       // anchors per thread
constexpr int TPB = 256;
constexpr int APB = TPB * R;               // anchors per block = 1024
constexpr int GX = (An + APB - 1) / APB;   // 118 blocks per image

// ws: per-block partials, block j=(b*GX+bx): [j*4 + {0:cls,1:reg,2:pos}]
__global__ __launch_bounds__(TPB, 4) void focal_main(
    const float* __restrict__ cls,
    const float* __restrict__ reg,
    const float* __restrict__ anchors,
    const float* __restrict__ ann,
    float* __restrict__ ws)
{
    // sT[k][0] = {x1,y1,x2,y2}; sT[k][1] = {sin,cos,area,clsval}
    __shared__ float4 sT[Mn][2];
    __shared__ float sred[4][3];

    const int tid = threadIdx.x;
    const int b = blockIdx.y;
    const int base = blockIdx.x * APB + tid;

    if (tid < Mn) {
        const float* a6 = ann + ((size_t)b * Mn + tid) * 6;
        float x1 = a6[0], y1 = a6[1], x2 = a6[2], y2 = a6[3];
        float cv = a6[4], fl = a6[5];
        float sb, cb;
        sincosf(cv, &sb, &cb);
        if (fl == -1.0f) { x1 = y1 = x2 = y2 = 0.f; sb = cb = 0.f; cv = 0.f; }
        sT[tid][0] = make_float4(x1, y1, x2, y2);
        sT[tid][1] = make_float4(sb, cb, (x2 - x1) * (y2 - y1), cv);
    }
    __syncthreads();

    // per-anchor persistent state
    float ax1[R], ay1[R], ax2[R], ay2[R], areaA[R], sa[R], ca[R], aangv[R];
    float bestA[R], bestB[R];
    int bestK[R];
    bool act[R];

    #pragma unroll
    for (int r = 0; r < R; ++r) {
        const int i = base + r * TPB;
        act[r] = (i < An);
        bestA[r] = 0.f; bestB[r] = 1.f; bestK[r] = 0;
        if (act[r]) {
            const float* a5 = anchors + (size_t)i * 5;
            ax1[r] = a5[0]; ay1[r] = a5[1]; ax2[r] = a5[2]; ay2[r] = a5[3];
            aangv[r] = a5[4];
            areaA[r] = (ax2[r] - ax1[r]) * (ay2[r] - ay1[r]);
            sincosf(aangv[r], &sa[r], &ca[r]);
        } else {
            ax1[r] = ay1[r] = ax2[r] = ay2[r] = 0.f;
            areaA[r] = 0.f; sa[r] = 0.f; ca[r] = 0.f; aangv[r] = 0.f;
        }
    }

    // argmax of ariou = (inter/ua)*|sin(aang-bang)| as rational (bestA/bestB).
    // cos(|d|-pi/2) == |sin d| for |d|<=pi (holds: aang in [0,pi), bang in {1,2,3}).
    // Strict-greater update -> first-occurrence, matching jnp.argmax.
    #pragma unroll 4
    for (int k = 0; k < Mn; ++k) {
        const float4 bx = sT[k][0];
        const float4 au = sT[k][1];   // {sinb, cosb, areaB, clsval}
        #pragma unroll
        for (int r = 0; r < R; ++r) {
            float iw = fminf(ax2[r], bx.z) - fmaxf(ax1[r], bx.x);
            float ih = fminf(ay2[r], bx.w) - fmaxf(ay1[r], bx.y);
            iw = fmaxf(iw, 0.f); ih = fmaxf(ih, 0.f);
            float inter = iw * ih;
            float ua = fmaxf(areaA[r] + au.z - inter, 1e-8f);
            float s = fabsf(sa[r] * au.y - ca[r] * au.x);   // |sin(aang-bang)|
            float av = inter * s;
            bool upd = (av * bestB[r] > bestA[r] * ua);
            bestA[r] = upd ? av : bestA[r];
            bestB[r] = upd ? ua : bestB[r];
            bestK[r] = upd ? k : bestK[r];
        }
    }

    float csum = 0.f, rsum = 0.f, pcnt = 0.f;

    #pragma unroll
    for (int r = 0; r < R; ++r) {
        if (!act[r]) continue;
        const int i = base + r * TPB;
        const float iou = bestA[r] / bestB[r];
        const bool pos = iou >= 0.5f;
        const bool neg = iou < 0.4f;

        if (pos || neg) {
            const float4 au = sT[bestK[r]][1];
            const int ci = (int)au.w;
            const float* pc = cls + ((size_t)b * An + i) * (size_t)Cn;
            #pragma unroll
            for (int c = 0; c < Cn; ++c) {
                float p = fminf(fmaxf(pc[c], 1e-4f), 0.9999f);
                bool hit = pos && (c == ci);
                float t = hit ? (1.f - p) : p;   // focal base
                float m = hit ? p : (1.f - p);   // log argument
                float w = hit ? 0.25f : 0.75f;
                csum += w * t * t * (-__logf(m));
            }
        }

        if (pos) {
            pcnt += 1.f;
            const float4 gb = sT[bestK[r]][0];
            const float4 au = sT[bestK[r]][1];
            float aw = ax2[r] - ax1[r], ah = ay2[r] - ay1[r];
            float acx = ax1[r] + 0.5f * aw, acy = ay1[r] + 0.5f * ah;
            float gwr = gb.z - gb.x, ghr = gb.w - gb.y;
            float gcx = gb.x + 0.5f * gwr, gcy = gb.y + 0.5f * ghr;
            float gw = fmaxf(gwr, 1.f), gh = fmaxf(ghr, 1.f);
            float tt[5];
            tt[0] = ((gcx - acx) / aw) * 10.f;
            tt[1] = ((gcy - acy) / ah) * 10.f;
            tt[2] = logf(gw / aw) * 5.f;
            tt[3] = logf(gh / ah) * 5.f;
            tt[4] = tanf(au.w - aangv[r]);
            const float* rg = reg + ((size_t)b * An + i) * 5;
            #pragma unroll
            for (int j = 0; j < 5; ++j) {
                float d = fabsf(tt[j] - rg[j]);
                rsum += (d <= (1.f / 9.f)) ? (4.5f * d * d) : (d - (0.5f / 9.f));
            }
        }
    }

    // wave reduce (64 lanes) then cross-wave via LDS
    #pragma unroll
    for (int off = 32; off > 0; off >>= 1) {
        csum += __shfl_down(csum, off, 64);
        rsum += __shfl_down(rsum, off, 64);
        pcnt += __shfl_down(pcnt, off, 64);
    }
    const int wave = tid >> 6;
    if ((tid & 63) == 0) {
        sred[wave][0] = csum; sred[wave][1] = rsum; sred[wave][2] = pcnt;
    }
    __syncthreads();
    if (tid == 0) {
        float c = sred[0][0] + sred[1][0] + sred[2][0] + sred[3][0];
        float r = sred[0][1] + sred[1][1] + sred[2][1] + sred[3][1];
        float p = sred[0][2] + sred[1][2] + sred[2][2] + sred[3][2];
        const int j = b * GX + blockIdx.x;
        ws[j * 4 + 0] = c;   // unconditional writes: no memset needed
        ws[j * 4 + 1] = r;
        ws[j * 4 + 2] = p;
    }
}

// 8 waves, wave w reduces image w's GX partials; then thread 0 means over B.
__global__ __launch_bounds__(512) void focal_final(
    const float* __restrict__ ann,
    const float* __restrict__ ws,
    float* __restrict__ out)
{
    __shared__ float simg[Bn][2];
    const int tid = threadIdx.x;
    const int w = tid >> 6;      // image
    const int lane = tid & 63;

    float c = 0.f, r = 0.f, p = 0.f;
    for (int j = lane; j < GX; j += 64) {
        const int idx = (w * GX + j) * 4;
        c += ws[idx + 0]; r += ws[idx + 1]; p += ws[idx + 2];
    }
    // has_ann: lane k checks ann[w][k] (Mn==64 lanes exactly)
    float fl = ann[((size_t)w * Mn + lane) * 6 + 5];
    bool has = __any(fl != -1.0f);

    #pragma unroll
    for (int off = 32; off > 0; off >>= 1) {
        c += __shfl_down(c, off, 64);
        r += __shfl_down(r, off, 64);
        p += __shfl_down(p, off, 64);
    }
    if (lane == 0) {
        float cl = 0.f, rl = 0.f;
        if (has) {
            cl = c / fmaxf(p, 1.f);
            rl = (p > 0.f) ? r / fmaxf(p * 5.f, 1.f) : 0.f;
        }
        simg[w][0] = cl; simg[w][1] = rl;
    }
    __syncthreads();
    if (tid == 0) {
        float cl = 0.f, rl = 0.f;
        #pragma unroll
        for (int b = 0; b < Bn; ++b) { cl += simg[b][0]; rl += simg[b][1]; }
        out[0] = cl / (float)Bn;
        out[1] = rl / (float)Bn;
    }
}

extern "C" void kernel_launch(void* const* d_in, const int* in_sizes, int n_in,
                              void* d_out, int out_size, void* d_ws, size_t ws_size,
                              hipStream_t stream) {
    const float* cls     = (const float*)d_in[0];  // (B, A, C)
    const float* reg     = (const float*)d_in[1];  // (B, A, 5)
    const float* anchors = (const float*)d_in[2];  // (1, A, 5)
    const float* ann     = (const float*)d_in[3];  // (B, M, 6)
    float* out = (float*)d_out;
    float* ws  = (float*)d_ws;

    dim3 grid(GX, Bn);
    focal_main<<<grid, TPB, 0, stream>>>(cls, reg, anchors, ann, ws);
    focal_final<<<1, 512, 0, stream>>>(ann, ws, out);
}